// Round 7
// baseline (668.070 us; speedup 1.0000x reference)
//
#include <hip/hip_runtime.h>
#include <hip/hip_fp16.h>

// ---------------------------------------------------------------------------
// Qwen2 attention block, MI355X (gfx950).
// B=2 S=2048 H=3584 NH=28 NKV=4 D=128  QS=3584 KVS=512 QKV=4608  M=B*S=4096
// fp16 MFMA (16x16x32) everywhere; fp32 accumulate; fp32 softmax/rope.
// R1: attention restructured for GQA K/V sharing — 7 waves/block = 7 q-heads.
// R2: attn __launch_bounds__(448,6) -> (448,2); ,6 capped VGPR at 40 -> spills.
// R3: GEMM BK=32 -> BK=64, (256,2) -> (256,4).
// R4: GEMM1 128x192-tile grid-exact kernel (24x32=768=3/CU), no tail.
// R5: attn LDS XOR-swizzle (conflicts 1.6e7 -> 9.5e5) but dbuf LDS 81920B ->
//     1 block/CU. LESSON: never size LDS to exact CU capacity.
// R6: attn single-buffered K/V + overlap via barrier placement. 179 -> ~164.
// R7: GEMMs: BK=32 dbuf, stage-before-compute, XOR-swizzle (conflicts
//     1.38e7 -> 0), setprio. gemm_wide 169 -> 159us (~851 TF, 2-phase ceiling).
// R8/R9: container infra failures (no verdict).
// R10: vtrans kernel (rope V-scatter removed), per-lane l_i deferral,
//     unconditional rescale. PASSED 665us. REVELATION: attn has been ~164us
//     since R6 — conflict/VALU/overlap fixes all null. Diagnosis: 1:1
//     ds_read_b128:MFMA ratio (16 kf + 16 vf per 32 MFMA) -> LDS-pipe-bound
//     (~245KB/tile/CU through one 128B/cy pipe); extra blocks just contend.
// R11: attn 32 q-rows/wave (grid 1024->512). Each kf read feeds 2 MFMAs
//     (two 16-row q groups), each vf read feeds 2 MFMAs (two P fragments
//     read together) -> b128 per FLOP cut 47%; barriers+staging per FLOP
//     halved. Ps -> [7][32][72] (LDS 65024B); VGPR ~180 -> 1 block/CU
//     (acceptable: blocks only contended for the LDS pipe). LPT pairing
//     balanced (~33 tile-units/CU).
// ---------------------------------------------------------------------------

typedef _Float16 h8 __attribute__((ext_vector_type(8)));
typedef _Float16 h4 __attribute__((ext_vector_type(4)));
typedef float f4 __attribute__((ext_vector_type(4)));

__device__ __forceinline__ void gload_lds16(const void* g, void* l) {
  __builtin_amdgcn_global_load_lds(
      (const __attribute__((address_space(1))) void*)g,
      (__attribute__((address_space(3))) void*)l, 16, 0, 0);
}

// ---------------- elementwise cast fp32 -> fp16 ----------------
__global__ __launch_bounds__(256)
void cast_f32_to_f16(const float4* __restrict__ in, h4* __restrict__ out, int n4) {
  int i = blockIdx.x * 256 + threadIdx.x;
  if (i < n4) {
    float4 v = in[i];
    h4 o;
    o.x = (_Float16)v.x; o.y = (_Float16)v.y; o.z = (_Float16)v.z; o.w = (_Float16)v.w;
    out[i] = o;
  }
}

// ---------------- transpose + cast: W[K][N] fp32 -> Wt[N][K] fp16 ----------------
__global__ __launch_bounds__(256)
void transpose_cast(const float* __restrict__ W, _Float16* __restrict__ Wt, int K, int N) {
  __shared__ float tile[32][33];
  int n0 = blockIdx.x * 32, k0 = blockIdx.y * 32;
  int tx = threadIdx.x, ty = threadIdx.y;   // block (32,8)
#pragma unroll
  for (int i = ty; i < 32; i += 8)
    tile[i][tx] = W[(size_t)(k0 + i) * N + n0 + tx];
  __syncthreads();
#pragma unroll
  for (int i = ty; i < 32; i += 8)
    Wt[(size_t)(n0 + i) * K + k0 + tx] = (_Float16)tile[tx][i];
}

// ---------------- V transpose: qkv V-cols -> Vt[b][kvh][d][S] ----------------
// grid (64, 16, 2) = 2048 blocks, block (32,8).
__global__ __launch_bounds__(256)
void vtrans(const _Float16* __restrict__ qkv, _Float16* __restrict__ vt) {
  constexpr int S = 2048, QKVW = 4608, VOFF = 4096;  // QW+KVW
  __shared__ _Float16 t[32][33];
  const int b = blockIdx.z, s0 = blockIdx.x * 32, d0 = blockIdx.y * 32;
  const int tx = threadIdx.x, ty = threadIdx.y;
#pragma unroll
  for (int i = ty; i < 32; i += 8)   // t[token][d]
    t[i][tx] = qkv[(size_t)(b * S + s0 + i) * QKVW + VOFF + d0 + tx];
  __syncthreads();
#pragma unroll
  for (int i = ty; i < 32; i += 8)   // vt[(b*512 + d)][s]
    vt[(size_t)(b * 512 + d0 + i) * S + s0 + tx] = t[tx][i];
}

// ---------------- GEMM1: 128x192 tile, grid-exact (24x32=768=3/CU) ----------
__global__ __launch_bounds__(256, 3)
void gemm_wide(const _Float16* __restrict__ A, const _Float16* __restrict__ Bt,
               const float* __restrict__ bias, _Float16* __restrict__ Cout,
               int M, int N, int K) {
  __shared__ _Float16 As[2][128 * 32];   // 2 x 8 KB
  __shared__ _Float16 Bs[2][192 * 32];   // 2 x 12 KB
  const int tid = threadIdx.x;
  const int m0 = blockIdx.y * 128, n0 = blockIdx.x * 192;
  const int lane = tid & 63, wave = tid >> 6;
  const int wm = (wave >> 1) * 64, wn = (wave & 1) * 96;
  const int r_ld = tid >> 2;          // staging row (0..63)
  const int c_swz = ((tid & 3) * 8) ^ (((r_ld >> 1) & 3) << 3);  // swizzled src col
  const int row_f = lane & 15, kg8 = (lane >> 4) * 8;
  const int kgx = kg8 ^ (((row_f >> 1) & 3) << 3);  // swizzled read col

  f4 acc[4][6] = {};
  const _Float16* Ag = A + (size_t)m0 * K + c_swz;
  const _Float16* Bg = Bt + (size_t)n0 * K + c_swz;

  auto stage = [&](int buf, int kk) {
#pragma unroll
    for (int i = 0; i < 2; ++i)
      gload_lds16(Ag + (size_t)(r_ld + i * 64) * K + kk,
                  &As[buf][0] + i * 2048 + tid * 8);
#pragma unroll
    for (int i = 0; i < 3; ++i)
      gload_lds16(Bg + (size_t)(r_ld + i * 64) * K + kk,
                  &Bs[buf][0] + i * 2048 + tid * 8);
  };

  // prologue
  stage(0, 0);
  asm volatile("s_waitcnt vmcnt(0)" ::: "memory");
  __builtin_amdgcn_s_barrier();
  __builtin_amdgcn_sched_barrier(0);

  int cur = 0;
  for (int kk = 0; kk < K; kk += 32) {
    if (kk + 32 < K) stage(cur ^ 1, kk + 32);
    __builtin_amdgcn_sched_barrier(0);

    h8 a_frag[4], b_frag[6];
#pragma unroll
    for (int t = 0; t < 4; ++t)
      a_frag[t] = *(const h8*)&As[cur][(wm + t * 16 + row_f) * 32 + kgx];
#pragma unroll
    for (int t = 0; t < 6; ++t)
      b_frag[t] = *(const h8*)&Bs[cur][(wn + t * 16 + row_f) * 32 + kgx];
    __builtin_amdgcn_s_setprio(1);
#pragma unroll
    for (int i = 0; i < 4; ++i)
#pragma unroll
      for (int j = 0; j < 6; ++j)
        acc[i][j] = __builtin_amdgcn_mfma_f32_16x16x32_f16(a_frag[i], b_frag[j], acc[i][j], 0, 0, 0);
    __builtin_amdgcn_s_setprio(0);

    __builtin_amdgcn_sched_barrier(0);
    asm volatile("s_waitcnt vmcnt(0)" ::: "memory");
    __builtin_amdgcn_s_barrier();
    __builtin_amdgcn_sched_barrier(0);
    cur ^= 1;
  }

  // epilogue: C/D layout col = lane&15, row = (lane>>4)*4 + r
  const int col_f = lane & 15, rgrp = (lane >> 4) * 4;
#pragma unroll
  for (int i = 0; i < 4; ++i) {
#pragma unroll
    for (int j = 0; j < 6; ++j) {
      const int col = n0 + wn + j * 16 + col_f;
      const float bv = bias[col];
#pragma unroll
      for (int r = 0; r < 4; ++r) {
        const int row = m0 + wm + i * 16 + rgrp + r;
        Cout[(size_t)row * N + col] = (_Float16)(acc[i][j][r] + bv);
      }
    }
  }
}

// ---------------- GEMM: C[M][N] = A[M][K] * Bt[N][K]^T (+bias) ----------------
template <bool OUT_H, bool BIAS>
__global__ __launch_bounds__(256, 4)
void gemm_kernel(const _Float16* __restrict__ A, const _Float16* __restrict__ Bt,
                 const float* __restrict__ bias, void* __restrict__ Cout,
                 int M, int N, int K) {
  __shared__ _Float16 As[2][128 * 32];
  __shared__ _Float16 Bs[2][128 * 32];
  const int tid = threadIdx.x;
  const int m0 = blockIdx.y * 128, n0 = blockIdx.x * 128;
  const int lane = tid & 63, wave = tid >> 6;
  const int wm = (wave >> 1) * 64, wn = (wave & 1) * 64;
  const int r_ld = tid >> 2;          // staging row (0..63)
  const int c_swz = ((tid & 3) * 8) ^ (((r_ld >> 1) & 3) << 3);
  const int row_f = lane & 15, kg8 = (lane >> 4) * 8;
  const int kgx = kg8 ^ (((row_f >> 1) & 3) << 3);

  f4 acc[4][4] = {};
  const _Float16* Ag = A + (size_t)m0 * K + c_swz;
  const _Float16* Bg = Bt + (size_t)n0 * K + c_swz;

  auto stage = [&](int buf, int kk) {
#pragma unroll
    for (int i = 0; i < 2; ++i) {
      gload_lds16(Ag + (size_t)(r_ld + i * 64) * K + kk,
                  &As[buf][0] + i * 2048 + tid * 8);
      gload_lds16(Bg + (size_t)(r_ld + i * 64) * K + kk,
                  &Bs[buf][0] + i * 2048 + tid * 8);
    }
  };

  stage(0, 0);
  asm volatile("s_waitcnt vmcnt(0)" ::: "memory");
  __builtin_amdgcn_s_barrier();
  __builtin_amdgcn_sched_barrier(0);

  int cur = 0;
  for (int kk = 0; kk < K; kk += 32) {
    if (kk + 32 < K) stage(cur ^ 1, kk + 32);
    __builtin_amdgcn_sched_barrier(0);

    h8 a_frag[4], b_frag[4];
#pragma unroll
    for (int t = 0; t < 4; ++t)
      a_frag[t] = *(const h8*)&As[cur][(wm + t * 16 + row_f) * 32 + kgx];
#pragma unroll
    for (int t = 0; t < 4; ++t)
      b_frag[t] = *(const h8*)&Bs[cur][(wn + t * 16 + row_f) * 32 + kgx];
    __builtin_amdgcn_s_setprio(1);
#pragma unroll
    for (int i = 0; i < 4; ++i)
#pragma unroll
      for (int j = 0; j < 4; ++j)
        acc[i][j] = __builtin_amdgcn_mfma_f32_16x16x32_f16(a_frag[i], b_frag[j], acc[i][j], 0, 0, 0);
    __builtin_amdgcn_s_setprio(0);

    __builtin_amdgcn_sched_barrier(0);
    asm volatile("s_waitcnt vmcnt(0)" ::: "memory");
    __builtin_amdgcn_s_barrier();
    __builtin_amdgcn_sched_barrier(0);
    cur ^= 1;
  }

  // epilogue: C/D layout col = lane&15, row = (lane>>4)*4 + r
  const int col_f = lane & 15, rgrp = (lane >> 4) * 4;
#pragma unroll
  for (int i = 0; i < 4; ++i) {
#pragma unroll
    for (int j = 0; j < 4; ++j) {
      const int col = n0 + wn + j * 16 + col_f;
      float bv = 0.0f;
      if (BIAS) bv = bias[col];
#pragma unroll
      for (int r = 0; r < 4; ++r) {
        const int row = m0 + wm + i * 16 + rgrp + r;
        const float v = acc[i][j][r] + bv;
        if (OUT_H) ((_Float16*)Cout)[(size_t)row * N + col] = (_Float16)v;
        else       ((float*)Cout)[(size_t)row * N + col] = v;
      }
    }
  }
}

// ---------------- RoPE + split (V handled by vtrans) ----------------
__global__ __launch_bounds__(256)
void rope_kernel(const _Float16* __restrict__ qkv, const int* __restrict__ pos,
                 _Float16* __restrict__ q, _Float16* __restrict__ k) {
  constexpr int NH = 28, NKV = 4, QKVW = 4608, QW = 3584, KVW = 512;
  const int token = blockIdx.x;
  const int p = pos[token];
  __shared__ float cs[64], sn[64];
  const int tid = threadIdx.x;
  if (tid < 64) {
    const float L = 0.31143075892695140f;  // log2(1e6)/64
    float inv = exp2f(-(float)tid * L);
    float ang = (float)p * inv;
    cs[tid] = cosf(ang);
    sn[tid] = sinf(ang);
  }
  __syncthreads();
  const _Float16* src = qkv + (size_t)token * QKVW;
  for (int i = tid; i < NH * 64; i += 256) {
    int hh = i >> 6, d = i & 63;
    float x1 = (float)src[hh * 128 + d];
    float x2 = (float)src[hh * 128 + d + 64];
    float c = cs[d], sv = sn[d];
    _Float16* dst = q + (size_t)token * QW + hh * 128 + d;
    dst[0]  = (_Float16)(x1 * c - x2 * sv);
    dst[64] = (_Float16)(x2 * c + x1 * sv);
  }
  for (int i = tid; i < NKV * 64; i += 256) {
    int hh = i >> 6, d = i & 63;
    float x1 = (float)src[QW + hh * 128 + d];
    float x2 = (float)src[QW + hh * 128 + d + 64];
    float c = cs[d], sv = sn[d];
    _Float16* dst = k + (size_t)token * KVW + hh * 128 + d;
    dst[0]  = (_Float16)(x1 * c - x2 * sv);
    dst[64] = (_Float16)(x2 * c + x1 * sv);
  }
}

// ---------------- flash attention (causal, GQA, KV shared across 7 heads) ----
// grid 512 blocks x 448 threads. Block = (32 q-rows) x (7 heads of one kvh).
// R11: each wave computes TWO 16-row q groups against the shared K/V tile:
// each kf/vf ds_read_b128 feeds 2 MFMAs -> LDS bytes per FLOP halved (the
// R6-R10 plateau was LDS-pipe-bound: 1:1 read:MFMA). Barriers/staging per
// FLOP also halved. Single-buffered K/V; stageV(kt) before QK^T, E=vmcnt+
// barrier, stageK(kt+1) before PV, G=vmcnt+barrier. XOR-swizzled K/V slots.
// l_i per-lane partials reduced in epilogue. LPT: qt descending.
// launch_bounds (448,2): VGPR cap 256 (VGPR ~180 -> 1 block/CU, accepted).
__global__ __launch_bounds__(448, 2)
void attn_kernel(const _Float16* __restrict__ Q,   // [B*S][NH*128] rope'd
                 const _Float16* __restrict__ Kh,  // [B*S][NKV*128] rope'd
                 const _Float16* __restrict__ Vt,  // [B][NKV][128][S]
                 _Float16* __restrict__ Oh) {      // [B*S][NH*128]
  constexpr int S = 2048, D = 128, NH = 28, NKV = 4;
  const int id = blockIdx.x;
  const int qt = 63 - (id >> 3);           // 32-row q tile, longest first
  const int b = (id >> 2) & 1, kvh = id & 3;
  const int tid = threadIdx.x, lane = tid & 63, wave = tid >> 6;  // wave 0..6
  const int h = kvh * 7 + wave;            // this wave's query head
  const int q0 = qt * 32;
  const int row_f = lane & 15, kg = lane >> 4, kg8 = (lane >> 4) * 8;
  const int kgx = kg8 ^ (((row_f >> 1) & 3) << 3);  // swizzled fragment column

  __shared__ _Float16 Ks[4][64][32];   // [d_chunk][key][32 d] = 16 KB
  __shared__ _Float16 Vs[2][128][32];  // [key_chunk][d][32 keys] = 16 KB
  __shared__ _Float16 Ps[7][32][72];   // per-wave P^T scratch (2 groups), 31.5 KB

  // load Q fragments for both 16-row groups (A-operand layout)
  h8 qf0[4], qf1[4];
  {
    const _Float16* qr0 = Q + ((size_t)(b * S + q0 + row_f) * NH + h) * D;
    const _Float16* qr1 = Q + ((size_t)(b * S + q0 + 16 + row_f) * NH + h) * D;
#pragma unroll
    for (int ks = 0; ks < 4; ++ks) {
      qf0[ks] = *(const h8*)(qr0 + ks * 32 + kg8);
      qf1[ks] = *(const h8*)(qr1 + ks * 32 + kg8);
    }
  }
  f4 o_acc0[8] = {}, o_acc1[8] = {};
  float m_i0[4] = {-1e30f, -1e30f, -1e30f, -1e30f};
  float m_i1[4] = {-1e30f, -1e30f, -1e30f, -1e30f};
  float l_i0[4] = {0.f, 0.f, 0.f, 0.f};   // per-lane partials
  float l_i1[4] = {0.f, 0.f, 0.f, 0.f};
  const float sc = 0.08838834764831845f * 1.4426950408889634f;  // scale * log2e

  const _Float16* kbase = Kh + ((size_t)(b * S) * NKV + kvh) * D;
  const _Float16* vbase = Vt + ((size_t)(b * NKV + kvh) * D) * S;

  const int kt_max = (q0 + 31) >> 6;  // last 64-key tile (diagonal)

  // stage K tile kt: 64 keys x 128 d; LDS dest lane-linear, global source
  // 16B-slot permuted by the same XOR the reads apply (involution).
  auto stageK = [&](int kt) {
#pragma unroll
    for (int is = 0; is < 4; ++is) {
      int off = (is * 256 + tid) * 8;
      int chunk = off >> 11;
      int key = (off >> 5) & 63;
      int dl = (off & 31) ^ (((key >> 1) & 3) << 3);
      gload_lds16(kbase + (size_t)(kt * 64 + key) * (NKV * D) + chunk * 32 + dl,
                  &Ks[0][0][0] + off);
    }
  };
  // stage V tile kt: 128 d x 64 keys
  auto stageV = [&](int kt) {
#pragma unroll
    for (int is = 0; is < 4; ++is) {
      int off = (is * 256 + tid) * 8;
      int chunk = off >> 12;
      int d = (off >> 5) & 127;
      int kl = (off & 31) ^ (((d >> 1) & 3) << 3);
      gload_lds16(vbase + (size_t)d * S + kt * 64 + chunk * 32 + kl,
                  &Vs[0][0][0] + off);
    }
  };

  // softmax for one 16-row group; writes P rows into Ps[wave][goff+..]
  auto softmax_g = [&](f4* s_acc, float* m_i, float* l_i, f4* o_acc,
                       int goff, bool diag, int kt) {
    float sv[4][4];
#pragma unroll
    for (int nt = 0; nt < 4; ++nt) {
#pragma unroll
      for (int r = 0; r < 4; ++r) {
        float v = s_acc[nt][r] * sc;
        if (diag) {
          int key = kt * 64 + nt * 16 + row_f;
          int row = q0 + goff + kg * 4 + r;
          if (key > row) v = -1e30f;
        }
        sv[nt][r] = v;
      }
    }
#pragma unroll
    for (int r = 0; r < 4; ++r) {
      float mx = fmaxf(fmaxf(sv[0][r], sv[1][r]), fmaxf(sv[2][r], sv[3][r]));
#pragma unroll
      for (int off = 8; off >= 1; off >>= 1)
        mx = fmaxf(mx, __shfl_xor(mx, off, 64));
      float mn = fmaxf(m_i[r], mx);
      float alpha = exp2f(m_i[r] - mn);
      m_i[r] = mn;
      float ls = 0.f;
#pragma unroll
      for (int nt = 0; nt < 4; ++nt) {
        float p = exp2f(sv[nt][r] - mn);
        sv[nt][r] = p;
        ls += p;
      }
      l_i[r] = l_i[r] * alpha + ls;
#pragma unroll
      for (int dt = 0; dt < 8; ++dt) o_acc[dt][r] *= alpha;
    }
#pragma unroll
    for (int nt = 0; nt < 4; ++nt)
#pragma unroll
      for (int r = 0; r < 4; ++r)
        Ps[wave][goff + kg * 4 + r][nt * 16 + row_f] = (_Float16)sv[nt][r];
  };

  // prologue: K(0) resident before first QK^T
  if (tid < 256) stageK(0);
  asm volatile("s_waitcnt vmcnt(0)" ::: "memory");
  __builtin_amdgcn_s_barrier();
  __builtin_amdgcn_sched_barrier(0);

  for (int kt = 0; kt <= kt_max; ++kt) {
    // issue V(kt) loads; they land during QK^T + softmax
    if (tid < 256) stageV(kt);
    __builtin_amdgcn_sched_barrier(0);

    // S = Q K^T  (32 q x 64 keys per wave; each kf feeds 2 MFMAs)
    f4 s0[4] = {}, s1[4] = {};
    __builtin_amdgcn_s_setprio(1);
#pragma unroll
    for (int ks = 0; ks < 4; ++ks) {
#pragma unroll
      for (int nt = 0; nt < 4; ++nt) {
        h8 kf = *(const h8*)&Ks[ks][nt * 16 + row_f][kgx];
        s0[nt] = __builtin_amdgcn_mfma_f32_16x16x32_f16(qf0[ks], kf, s0[nt], 0, 0, 0);
        s1[nt] = __builtin_amdgcn_mfma_f32_16x16x32_f16(qf1[ks], kf, s1[nt], 0, 0, 0);
      }
    }
    __builtin_amdgcn_s_setprio(0);

    const bool diag = (kt == kt_max);
    softmax_g(s0, m_i0, l_i0, o_acc0, 0, diag, kt);
    softmax_g(s1, m_i1, l_i1, o_acc1, 16, diag, kt);

    // E: V(kt) landed; all waves done reading Ks -> safe to overwrite.
    __builtin_amdgcn_sched_barrier(0);
    asm volatile("s_waitcnt vmcnt(0)" ::: "memory");
    __builtin_amdgcn_s_barrier();
    __builtin_amdgcn_sched_barrier(0);

    // issue K(kt+1) loads; they land during PV
    if (kt < kt_max && tid < 256) stageK(kt + 1);
    __builtin_amdgcn_sched_barrier(0);

    // O += P V  (each vf feeds 2 MFMAs)
    __builtin_amdgcn_s_setprio(1);
#pragma unroll
    for (int kv = 0; kv < 2; ++kv) {
      h8 pf0 = *(const h8*)&Ps[wave][row_f][kv * 32 + kg8];
      h8 pf1 = *(const h8*)&Ps[wave][16 + row_f][kv * 32 + kg8];
#pragma unroll
      for (int dt = 0; dt < 8; ++dt) {
        h8 vf = *(const h8*)&Vs[kv][dt * 16 + row_f][kgx];
        o_acc0[dt] = __builtin_amdgcn_mfma_f32_16x16x32_f16(pf0, vf, o_acc0[dt], 0, 0, 0);
        o_acc1[dt] = __builtin_amdgcn_mfma_f32_16x16x32_f16(pf1, vf, o_acc1[dt], 0, 0, 0);
      }
    }
    __builtin_amdgcn_s_setprio(0);

    // G: K(kt+1) landed; all waves done reading Vs -> next stageV safe.
    __builtin_amdgcn_sched_barrier(0);
    asm volatile("s_waitcnt vmcnt(0)" ::: "memory");
    __builtin_amdgcn_s_barrier();
    __builtin_amdgcn_sched_barrier(0);
  }

  // epilogue: reduce l across the 16-lane row group, O /= l, store
  float inv_l0[4], inv_l1[4];
#pragma unroll
  for (int r = 0; r < 4; ++r) {
    float ls0 = l_i0[r], ls1 = l_i1[r];
#pragma unroll
    for (int off = 8; off >= 1; off >>= 1) {
      ls0 += __shfl_xor(ls0, off, 64);
      ls1 += __shfl_xor(ls1, off, 64);
    }
    inv_l0[r] = 1.0f / ls0;
    inv_l1[r] = 1.0f / ls1;
  }
#pragma unroll
  for (int dt = 0; dt < 8; ++dt) {
#pragma unroll
    for (int r = 0; r < 4; ++r) {
      const int tok0 = b * S + q0 + kg * 4 + r;
      const int d = dt * 16 + row_f;
      Oh[((size_t)tok0 * NH + h) * D + d] = (_Float16)(o_acc0[dt][r] * inv_l0[r]);
      Oh[((size_t)(tok0 + 16) * NH + h) * D + d] = (_Float16)(o_acc1[dt][r] * inv_l1[r]);
    }
  }
}

// ---------------------------------------------------------------------------
extern "C" void kernel_launch(void* const* d_in, const int* in_sizes, int n_in,
                              void* d_out, int out_size, void* d_ws, size_t ws_size,
                              hipStream_t stream) {
  const float* hidden    = (const float*)d_in[0];
  const int*   positions = (const int*)d_in[1];
  const float* Wqkv      = (const float*)d_in[2];
  const float* bqkv      = (const float*)d_in[3];
  const float* Wo        = (const float*)d_in[4];
  float* out = (float*)d_out;

  // workspace layout (bytes)
  char* ws = (char*)d_ws;
  _Float16* hs_h  = (_Float16*)(ws);              // 4096x3584 fp16 (later reused as attn out)
  _Float16* Wt    = (_Float16*)(ws + 29360128);   // max 4608x3584 fp16 (Wqkv^T then Wo^T)
  _Float16* qkv_h = (_Float16*)(ws + 62390272);   // 4096x4608 fp16
  _Float16* q_h   = (_Float16*)(ws + 100139008);  // 4096x3584 fp16
  _Float16* k_h   = (_Float16*)(ws + 129499136);  // 4096x512 fp16
  _Float16* vt_h  = (_Float16*)(ws + 133693440);  // 2x4x128x2048 fp16
  // total 137,887,744 bytes

  // 1. hidden fp32 -> fp16
  cast_f32_to_f16<<<14336, 256, 0, stream>>>((const float4*)hidden, (h4*)hs_h, 3670016);
  // 2. Wqkv^T fp16
  transpose_cast<<<dim3(4608 / 32, 3584 / 32), dim3(32, 8), 0, stream>>>(Wqkv, Wt, 3584, 4608);
  // 3. qkv = hidden @ Wqkv + b   (fp16 out) — 128x192 tiles, grid-exact 768
  gemm_wide<<<dim3(24, 32), 256, 0, stream>>>(hs_h, Wt, bqkv, qkv_h, 4096, 4608, 3584);
  // 4a. rope (q,k) — V no longer scattered here
  rope_kernel<<<4096, 256, 0, stream>>>(qkv_h, positions, q_h, k_h);
  // 4b. V transpose (LDS-tiled, coalesced)
  vtrans<<<dim3(64, 16, 2), dim3(32, 8), 0, stream>>>(qkv_h, vt_h);
  // 5. Wo^T fp16 (reuse Wt; stream-ordered after GEMM1)
  transpose_cast<<<dim3(3584 / 32, 3584 / 32), dim3(32, 8), 0, stream>>>(Wo, Wt, 3584, 3584);
  // 6. flash attention -> attn fp16 (into hs_h, dead after GEMM1)
  attn_kernel<<<512, 448, 0, stream>>>(q_h, k_h, vt_h, hs_h);
  // 7. out = attn @ Wo   (fp32 out)
  gemm_kernel<false, false><<<dim3(28, 32), 256, 0, stream>>>(hs_h, Wt, nullptr, out, 4096, 3584, 3584);
}

// Round 8
// 618.518 us; speedup vs baseline: 1.0801x; 1.0801x over previous
//
#include <hip/hip_runtime.h>
#include <hip/hip_fp16.h>

// ---------------------------------------------------------------------------
// Qwen2 attention block, MI355X (gfx950).
// B=2 S=2048 H=3584 NH=28 NKV=4 D=128  QS=3584 KVS=512 QKV=4608  M=B*S=4096
// fp16 MFMA (16x16x32) everywhere; fp32 accumulate; fp32 softmax/rope.
// R1-R10: see git history. Key verified facts: attn XOR-swizzle kills bank
//     conflicts (1.6e7->9.5e5); GEMMs at 2-phase ceiling (~851 TF); LDS must
//     not be sized to exact CU capacity; vtrans replaced rope V-scatter.
// R11: 32 q-rows/wave (2 groups/wave, grid 512) — NULL (162 vs 164us).
//     Post-mortem: halving kf/vf b128 per FLOP didn't move time because the
//     dominant per-FLOP DS load is the SOFTMAX cross-lane machinery:
//     32 shfl_xor (4-deep dependent chains) + 32 scalar Ps writes + rescale
//     VALU per wave-tile. VALUBusy:MfmaUtil = 43:16 matches that ratio.
// R12: (a) TRUE T13 gate: per-lane partial max (3 fmax, no shfl) +
//     __all(pmax <= m+8) (exec-mask op, zero DS) -> skip BOTH the 4-deep
//     shfl-max chain AND the rescale in the common case (P <= 2^8, fp16-safe;
//     first tile m=-1e30 forces exact path). R8's version kept the shfl
//     reduce every tile — this removes it. (b) fold scale*log2e into Q at
//     rope (Q is attn-only): removes 32 VALU mul/wave-tile. GEMMs unchanged.
// ---------------------------------------------------------------------------

typedef _Float16 h8 __attribute__((ext_vector_type(8)));
typedef _Float16 h4 __attribute__((ext_vector_type(4)));
typedef float f4 __attribute__((ext_vector_type(4)));

__device__ __forceinline__ void gload_lds16(const void* g, void* l) {
  __builtin_amdgcn_global_load_lds(
      (const __attribute__((address_space(1))) void*)g,
      (__attribute__((address_space(3))) void*)l, 16, 0, 0);
}

// ---------------- elementwise cast fp32 -> fp16 ----------------
__global__ __launch_bounds__(256)
void cast_f32_to_f16(const float4* __restrict__ in, h4* __restrict__ out, int n4) {
  int i = blockIdx.x * 256 + threadIdx.x;
  if (i < n4) {
    float4 v = in[i];
    h4 o;
    o.x = (_Float16)v.x; o.y = (_Float16)v.y; o.z = (_Float16)v.z; o.w = (_Float16)v.w;
    out[i] = o;
  }
}

// ---------------- transpose + cast: W[K][N] fp32 -> Wt[N][K] fp16 ----------------
__global__ __launch_bounds__(256)
void transpose_cast(const float* __restrict__ W, _Float16* __restrict__ Wt, int K, int N) {
  __shared__ float tile[32][33];
  int n0 = blockIdx.x * 32, k0 = blockIdx.y * 32;
  int tx = threadIdx.x, ty = threadIdx.y;   // block (32,8)
#pragma unroll
  for (int i = ty; i < 32; i += 8)
    tile[i][tx] = W[(size_t)(k0 + i) * N + n0 + tx];
  __syncthreads();
#pragma unroll
  for (int i = ty; i < 32; i += 8)
    Wt[(size_t)(n0 + i) * K + k0 + tx] = (_Float16)tile[tx][i];
}

// ---------------- V transpose: qkv V-cols -> Vt[b][kvh][d][S] ----------------
// grid (64, 16, 2) = 2048 blocks, block (32,8).
__global__ __launch_bounds__(256)
void vtrans(const _Float16* __restrict__ qkv, _Float16* __restrict__ vt) {
  constexpr int S = 2048, QKVW = 4608, VOFF = 4096;  // QW+KVW
  __shared__ _Float16 t[32][33];
  const int b = blockIdx.z, s0 = blockIdx.x * 32, d0 = blockIdx.y * 32;
  const int tx = threadIdx.x, ty = threadIdx.y;
#pragma unroll
  for (int i = ty; i < 32; i += 8)   // t[token][d]
    t[i][tx] = qkv[(size_t)(b * S + s0 + i) * QKVW + VOFF + d0 + tx];
  __syncthreads();
#pragma unroll
  for (int i = ty; i < 32; i += 8)   // vt[(b*512 + d)][s]
    vt[(size_t)(b * 512 + d0 + i) * S + s0 + tx] = t[tx][i];
}

// ---------------- GEMM1: 128x192 tile, grid-exact (24x32=768=3/CU) ----------
__global__ __launch_bounds__(256, 3)
void gemm_wide(const _Float16* __restrict__ A, const _Float16* __restrict__ Bt,
               const float* __restrict__ bias, _Float16* __restrict__ Cout,
               int M, int N, int K) {
  __shared__ _Float16 As[2][128 * 32];   // 2 x 8 KB
  __shared__ _Float16 Bs[2][192 * 32];   // 2 x 12 KB
  const int tid = threadIdx.x;
  const int m0 = blockIdx.y * 128, n0 = blockIdx.x * 192;
  const int lane = tid & 63, wave = tid >> 6;
  const int wm = (wave >> 1) * 64, wn = (wave & 1) * 96;
  const int r_ld = tid >> 2;          // staging row (0..63)
  const int c_swz = ((tid & 3) * 8) ^ (((r_ld >> 1) & 3) << 3);  // swizzled src col
  const int row_f = lane & 15, kg8 = (lane >> 4) * 8;
  const int kgx = kg8 ^ (((row_f >> 1) & 3) << 3);  // swizzled read col

  f4 acc[4][6] = {};
  const _Float16* Ag = A + (size_t)m0 * K + c_swz;
  const _Float16* Bg = Bt + (size_t)n0 * K + c_swz;

  auto stage = [&](int buf, int kk) {
#pragma unroll
    for (int i = 0; i < 2; ++i)
      gload_lds16(Ag + (size_t)(r_ld + i * 64) * K + kk,
                  &As[buf][0] + i * 2048 + tid * 8);
#pragma unroll
    for (int i = 0; i < 3; ++i)
      gload_lds16(Bg + (size_t)(r_ld + i * 64) * K + kk,
                  &Bs[buf][0] + i * 2048 + tid * 8);
  };

  // prologue
  stage(0, 0);
  asm volatile("s_waitcnt vmcnt(0)" ::: "memory");
  __builtin_amdgcn_s_barrier();
  __builtin_amdgcn_sched_barrier(0);

  int cur = 0;
  for (int kk = 0; kk < K; kk += 32) {
    if (kk + 32 < K) stage(cur ^ 1, kk + 32);
    __builtin_amdgcn_sched_barrier(0);

    h8 a_frag[4], b_frag[6];
#pragma unroll
    for (int t = 0; t < 4; ++t)
      a_frag[t] = *(const h8*)&As[cur][(wm + t * 16 + row_f) * 32 + kgx];
#pragma unroll
    for (int t = 0; t < 6; ++t)
      b_frag[t] = *(const h8*)&Bs[cur][(wn + t * 16 + row_f) * 32 + kgx];
    __builtin_amdgcn_s_setprio(1);
#pragma unroll
    for (int i = 0; i < 4; ++i)
#pragma unroll
      for (int j = 0; j < 6; ++j)
        acc[i][j] = __builtin_amdgcn_mfma_f32_16x16x32_f16(a_frag[i], b_frag[j], acc[i][j], 0, 0, 0);
    __builtin_amdgcn_s_setprio(0);

    __builtin_amdgcn_sched_barrier(0);
    asm volatile("s_waitcnt vmcnt(0)" ::: "memory");
    __builtin_amdgcn_s_barrier();
    __builtin_amdgcn_sched_barrier(0);
    cur ^= 1;
  }

  // epilogue: C/D layout col = lane&15, row = (lane>>4)*4 + r
  const int col_f = lane & 15, rgrp = (lane >> 4) * 4;
#pragma unroll
  for (int i = 0; i < 4; ++i) {
#pragma unroll
    for (int j = 0; j < 6; ++j) {
      const int col = n0 + wn + j * 16 + col_f;
      const float bv = bias[col];
#pragma unroll
      for (int r = 0; r < 4; ++r) {
        const int row = m0 + wm + i * 16 + rgrp + r;
        Cout[(size_t)row * N + col] = (_Float16)(acc[i][j][r] + bv);
      }
    }
  }
}

// ---------------- GEMM: C[M][N] = A[M][K] * Bt[N][K]^T (+bias) ----------------
template <bool OUT_H, bool BIAS>
__global__ __launch_bounds__(256, 4)
void gemm_kernel(const _Float16* __restrict__ A, const _Float16* __restrict__ Bt,
                 const float* __restrict__ bias, void* __restrict__ Cout,
                 int M, int N, int K) {
  __shared__ _Float16 As[2][128 * 32];
  __shared__ _Float16 Bs[2][128 * 32];
  const int tid = threadIdx.x;
  const int m0 = blockIdx.y * 128, n0 = blockIdx.x * 128;
  const int lane = tid & 63, wave = tid >> 6;
  const int wm = (wave >> 1) * 64, wn = (wave & 1) * 64;
  const int r_ld = tid >> 2;          // staging row (0..63)
  const int c_swz = ((tid & 3) * 8) ^ (((r_ld >> 1) & 3) << 3);
  const int row_f = lane & 15, kg8 = (lane >> 4) * 8;
  const int kgx = kg8 ^ (((row_f >> 1) & 3) << 3);

  f4 acc[4][4] = {};
  const _Float16* Ag = A + (size_t)m0 * K + c_swz;
  const _Float16* Bg = Bt + (size_t)n0 * K + c_swz;

  auto stage = [&](int buf, int kk) {
#pragma unroll
    for (int i = 0; i < 2; ++i) {
      gload_lds16(Ag + (size_t)(r_ld + i * 64) * K + kk,
                  &As[buf][0] + i * 2048 + tid * 8);
      gload_lds16(Bg + (size_t)(r_ld + i * 64) * K + kk,
                  &Bs[buf][0] + i * 2048 + tid * 8);
    }
  };

  stage(0, 0);
  asm volatile("s_waitcnt vmcnt(0)" ::: "memory");
  __builtin_amdgcn_s_barrier();
  __builtin_amdgcn_sched_barrier(0);

  int cur = 0;
  for (int kk = 0; kk < K; kk += 32) {
    if (kk + 32 < K) stage(cur ^ 1, kk + 32);
    __builtin_amdgcn_sched_barrier(0);

    h8 a_frag[4], b_frag[4];
#pragma unroll
    for (int t = 0; t < 4; ++t)
      a_frag[t] = *(const h8*)&As[cur][(wm + t * 16 + row_f) * 32 + kgx];
#pragma unroll
    for (int t = 0; t < 4; ++t)
      b_frag[t] = *(const h8*)&Bs[cur][(wn + t * 16 + row_f) * 32 + kgx];
    __builtin_amdgcn_s_setprio(1);
#pragma unroll
    for (int i = 0; i < 4; ++i)
#pragma unroll
      for (int j = 0; j < 4; ++j)
        acc[i][j] = __builtin_amdgcn_mfma_f32_16x16x32_f16(a_frag[i], b_frag[j], acc[i][j], 0, 0, 0);
    __builtin_amdgcn_s_setprio(0);

    __builtin_amdgcn_sched_barrier(0);
    asm volatile("s_waitcnt vmcnt(0)" ::: "memory");
    __builtin_amdgcn_s_barrier();
    __builtin_amdgcn_sched_barrier(0);
    cur ^= 1;
  }

  // epilogue: C/D layout col = lane&15, row = (lane>>4)*4 + r
  const int col_f = lane & 15, rgrp = (lane >> 4) * 4;
#pragma unroll
  for (int i = 0; i < 4; ++i) {
#pragma unroll
    for (int j = 0; j < 4; ++j) {
      const int col = n0 + wn + j * 16 + col_f;
      float bv = 0.0f;
      if (BIAS) bv = bias[col];
#pragma unroll
      for (int r = 0; r < 4; ++r) {
        const int row = m0 + wm + i * 16 + rgrp + r;
        const float v = acc[i][j][r] + bv;
        if (OUT_H) ((_Float16*)Cout)[(size_t)row * N + col] = (_Float16)v;
        else       ((float*)Cout)[(size_t)row * N + col] = v;
      }
    }
  }
}

// ---------------- RoPE + split (V handled by vtrans) ----------------
// R12: Q outputs pre-scaled by head_dim^-0.5 * log2(e) so attn's QK^T
// scores are already in the exp2 domain (saves 32 VALU mul per wave-tile).
__global__ __launch_bounds__(256)
void rope_kernel(const _Float16* __restrict__ qkv, const int* __restrict__ pos,
                 _Float16* __restrict__ q, _Float16* __restrict__ k) {
  constexpr int NH = 28, NKV = 4, QKVW = 4608, QW = 3584, KVW = 512;
  constexpr float SCL = 0.12751743767f;  // 0.08838834765 * 1.44269504089
  const int token = blockIdx.x;
  const int p = pos[token];
  __shared__ float cs[64], sn[64];
  const int tid = threadIdx.x;
  if (tid < 64) {
    const float L = 0.31143075892695140f;  // log2(1e6)/64
    float inv = exp2f(-(float)tid * L);
    float ang = (float)p * inv;
    cs[tid] = cosf(ang);
    sn[tid] = sinf(ang);
  }
  __syncthreads();
  const _Float16* src = qkv + (size_t)token * QKVW;
  for (int i = tid; i < NH * 64; i += 256) {
    int hh = i >> 6, d = i & 63;
    float x1 = (float)src[hh * 128 + d];
    float x2 = (float)src[hh * 128 + d + 64];
    float c = cs[d], sv = sn[d];
    _Float16* dst = q + (size_t)token * QW + hh * 128 + d;
    dst[0]  = (_Float16)((x1 * c - x2 * sv) * SCL);
    dst[64] = (_Float16)((x2 * c + x1 * sv) * SCL);
  }
  for (int i = tid; i < NKV * 64; i += 256) {
    int hh = i >> 6, d = i & 63;
    float x1 = (float)src[QW + hh * 128 + d];
    float x2 = (float)src[QW + hh * 128 + d + 64];
    float c = cs[d], sv = sn[d];
    _Float16* dst = k + (size_t)token * KVW + hh * 128 + d;
    dst[0]  = (_Float16)(x1 * c - x2 * sv);
    dst[64] = (_Float16)(x2 * c + x1 * sv);
  }
}

// ---------------- flash attention (causal, GQA, KV shared across 7 heads) ----
// grid 512 blocks x 448 threads. Block = (32 q-rows) x (7 heads of one kvh).
// Each wave: two 16-row q groups; kf/vf b128 reads feed 2 MFMAs each.
// Single-buffered K/V; stageV(kt) before QK^T, E=vmcnt+barrier, stageK(kt+1)
// before PV, G=vmcnt+barrier. XOR-swizzled K/V slots.
// R12 softmax: TRUE T13 — per-lane partial max + __all gate (no DS ops);
// shfl-max chain + rescale only on the rare exact path. Scores arrive
// pre-scaled (exp2 domain) from rope. l_i per-lane partials, epilogue-reduced.
// launch_bounds (448,2): VGPR cap 256 — DO NOT tighten.
__global__ __launch_bounds__(448, 2)
void attn_kernel(const _Float16* __restrict__ Q,   // [B*S][NH*128] rope'd, pre-scaled
                 const _Float16* __restrict__ Kh,  // [B*S][NKV*128] rope'd
                 const _Float16* __restrict__ Vt,  // [B][NKV][128][S]
                 _Float16* __restrict__ Oh) {      // [B*S][NH*128]
  constexpr int S = 2048, D = 128, NH = 28, NKV = 4;
  const int id = blockIdx.x;
  const int qt = 63 - (id >> 3);           // 32-row q tile, longest first
  const int b = (id >> 2) & 1, kvh = id & 3;
  const int tid = threadIdx.x, lane = tid & 63, wave = tid >> 6;  // wave 0..6
  const int h = kvh * 7 + wave;            // this wave's query head
  const int q0 = qt * 32;
  const int row_f = lane & 15, kg = lane >> 4, kg8 = (lane >> 4) * 8;
  const int kgx = kg8 ^ (((row_f >> 1) & 3) << 3);  // swizzled fragment column

  __shared__ _Float16 Ks[4][64][32];   // [d_chunk][key][32 d] = 16 KB
  __shared__ _Float16 Vs[2][128][32];  // [key_chunk][d][32 keys] = 16 KB
  __shared__ _Float16 Ps[7][32][72];   // per-wave P^T scratch (2 groups)

  // load Q fragments for both 16-row groups (A-operand layout)
  h8 qf0[4], qf1[4];
  {
    const _Float16* qr0 = Q + ((size_t)(b * S + q0 + row_f) * NH + h) * D;
    const _Float16* qr1 = Q + ((size_t)(b * S + q0 + 16 + row_f) * NH + h) * D;
#pragma unroll
    for (int ks = 0; ks < 4; ++ks) {
      qf0[ks] = *(const h8*)(qr0 + ks * 32 + kg8);
      qf1[ks] = *(const h8*)(qr1 + ks * 32 + kg8);
    }
  }
  f4 o_acc0[8] = {}, o_acc1[8] = {};
  float m_i0[4] = {-1e30f, -1e30f, -1e30f, -1e30f};
  float m_i1[4] = {-1e30f, -1e30f, -1e30f, -1e30f};
  float l_i0[4] = {0.f, 0.f, 0.f, 0.f};   // per-lane partials
  float l_i1[4] = {0.f, 0.f, 0.f, 0.f};

  const _Float16* kbase = Kh + ((size_t)(b * S) * NKV + kvh) * D;
  const _Float16* vbase = Vt + ((size_t)(b * NKV + kvh) * D) * S;

  const int kt_max = (q0 + 31) >> 6;  // last 64-key tile (diagonal)

  // stage K tile kt: 64 keys x 128 d; LDS dest lane-linear, global source
  // 16B-slot permuted by the same XOR the reads apply (involution).
  auto stageK = [&](int kt) {
#pragma unroll
    for (int is = 0; is < 4; ++is) {
      int off = (is * 256 + tid) * 8;
      int chunk = off >> 11;
      int key = (off >> 5) & 63;
      int dl = (off & 31) ^ (((key >> 1) & 3) << 3);
      gload_lds16(kbase + (size_t)(kt * 64 + key) * (NKV * D) + chunk * 32 + dl,
                  &Ks[0][0][0] + off);
    }
  };
  // stage V tile kt: 128 d x 64 keys
  auto stageV = [&](int kt) {
#pragma unroll
    for (int is = 0; is < 4; ++is) {
      int off = (is * 256 + tid) * 8;
      int chunk = off >> 12;
      int d = (off >> 5) & 127;
      int kl = (off & 31) ^ (((d >> 1) & 3) << 3);
      gload_lds16(vbase + (size_t)d * S + kt * 64 + chunk * 32 + kl,
                  &Vs[0][0][0] + off);
    }
  };

  // softmax for one 16-row group; writes P rows into Ps[wave][goff+..]
  // T13: per-lane partial max gate; shfl reduce + rescale only when exceeded.
  auto softmax_g = [&](f4* s_acc, float* m_i, float* l_i, f4* o_acc,
                       int goff, bool diag, int kt) {
    float sv[4][4];
#pragma unroll
    for (int nt = 0; nt < 4; ++nt) {
#pragma unroll
      for (int r = 0; r < 4; ++r) {
        float v = s_acc[nt][r];   // already scaled (rope pre-scale)
        if (diag) {
          int key = kt * 64 + nt * 16 + row_f;
          int row = q0 + goff + kg * 4 + r;
          if (key > row) v = -1e30f;
        }
        sv[nt][r] = v;
      }
    }
    // per-lane partial max (no cross-lane traffic)
    float pmax[4];
    bool ok = true;
#pragma unroll
    for (int r = 0; r < 4; ++r) {
      pmax[r] = fmaxf(fmaxf(sv[0][r], sv[1][r]), fmaxf(sv[2][r], sv[3][r]));
      ok = ok && (pmax[r] <= m_i[r] + 8.0f);
    }
    if (!__all(ok)) {
      // exact path: wave max per row + rescale (rare; always taken tile 0)
#pragma unroll
      for (int r = 0; r < 4; ++r) {
        float mx = pmax[r];
#pragma unroll
        for (int off = 8; off >= 1; off >>= 1)
          mx = fmaxf(mx, __shfl_xor(mx, off, 64));
        float mn = fmaxf(m_i[r], mx);
        float alpha = exp2f(m_i[r] - mn);
        m_i[r] = mn;
        l_i[r] *= alpha;
#pragma unroll
        for (int dt = 0; dt < 8; ++dt) o_acc[dt][r] *= alpha;
      }
    }
#pragma unroll
    for (int r = 0; r < 4; ++r) {
      float ls = 0.f;
#pragma unroll
      for (int nt = 0; nt < 4; ++nt) {
        float p = exp2f(sv[nt][r] - m_i[r]);   // bounded by 2^8 when gated
        sv[nt][r] = p;
        ls += p;
      }
      l_i[r] += ls;
    }
#pragma unroll
    for (int nt = 0; nt < 4; ++nt)
#pragma unroll
      for (int r = 0; r < 4; ++r)
        Ps[wave][goff + kg * 4 + r][nt * 16 + row_f] = (_Float16)sv[nt][r];
  };

  // prologue: K(0) resident before first QK^T
  if (tid < 256) stageK(0);
  asm volatile("s_waitcnt vmcnt(0)" ::: "memory");
  __builtin_amdgcn_s_barrier();
  __builtin_amdgcn_sched_barrier(0);

  for (int kt = 0; kt <= kt_max; ++kt) {
    // issue V(kt) loads; they land during QK^T + softmax
    if (tid < 256) stageV(kt);
    __builtin_amdgcn_sched_barrier(0);

    // S = Q K^T  (32 q x 64 keys per wave; each kf feeds 2 MFMAs)
    f4 s0[4] = {}, s1[4] = {};
    __builtin_amdgcn_s_setprio(1);
#pragma unroll
    for (int ks = 0; ks < 4; ++ks) {
#pragma unroll
      for (int nt = 0; nt < 4; ++nt) {
        h8 kf = *(const h8*)&Ks[ks][nt * 16 + row_f][kgx];
        s0[nt] = __builtin_amdgcn_mfma_f32_16x16x32_f16(qf0[ks], kf, s0[nt], 0, 0, 0);
        s1[nt] = __builtin_amdgcn_mfma_f32_16x16x32_f16(qf1[ks], kf, s1[nt], 0, 0, 0);
      }
    }
    __builtin_amdgcn_s_setprio(0);

    const bool diag = (kt == kt_max);
    softmax_g(s0, m_i0, l_i0, o_acc0, 0, diag, kt);
    softmax_g(s1, m_i1, l_i1, o_acc1, 16, diag, kt);

    // E: V(kt) landed; all waves done reading Ks -> safe to overwrite.
    __builtin_amdgcn_sched_barrier(0);
    asm volatile("s_waitcnt vmcnt(0)" ::: "memory");
    __builtin_amdgcn_s_barrier();
    __builtin_amdgcn_sched_barrier(0);

    // issue K(kt+1) loads; they land during PV
    if (kt < kt_max && tid < 256) stageK(kt + 1);
    __builtin_amdgcn_sched_barrier(0);

    // O += P V  (each vf feeds 2 MFMAs)
    __builtin_amdgcn_s_setprio(1);
#pragma unroll
    for (int kv = 0; kv < 2; ++kv) {
      h8 pf0 = *(const h8*)&Ps[wave][row_f][kv * 32 + kg8];
      h8 pf1 = *(const h8*)&Ps[wave][16 + row_f][kv * 32 + kg8];
#pragma unroll
      for (int dt = 0; dt < 8; ++dt) {
        h8 vf = *(const h8*)&Vs[kv][dt * 16 + row_f][kgx];
        o_acc0[dt] = __builtin_amdgcn_mfma_f32_16x16x32_f16(pf0, vf, o_acc0[dt], 0, 0, 0);
        o_acc1[dt] = __builtin_amdgcn_mfma_f32_16x16x32_f16(pf1, vf, o_acc1[dt], 0, 0, 0);
      }
    }
    __builtin_amdgcn_s_setprio(0);

    // G: K(kt+1) landed; all waves done reading Vs -> next stageV safe.
    __builtin_amdgcn_sched_barrier(0);
    asm volatile("s_waitcnt vmcnt(0)" ::: "memory");
    __builtin_amdgcn_s_barrier();
    __builtin_amdgcn_sched_barrier(0);
  }

  // epilogue: reduce l across the 16-lane row group, O /= l, store
  float inv_l0[4], inv_l1[4];
#pragma unroll
  for (int r = 0; r < 4; ++r) {
    float ls0 = l_i0[r], ls1 = l_i1[r];
#pragma unroll
    for (int off = 8; off >= 1; off >>= 1) {
      ls0 += __shfl_xor(ls0, off, 64);
      ls1 += __shfl_xor(ls1, off, 64);
    }
    inv_l0[r] = 1.0f / ls0;
    inv_l1[r] = 1.0f / ls1;
  }
#pragma unroll
  for (int dt = 0; dt < 8; ++dt) {
#pragma unroll
    for (int r = 0; r < 4; ++r) {
      const int tok0 = b * S + q0 + kg * 4 + r;
      const int d = dt * 16 + row_f;
      Oh[((size_t)tok0 * NH + h) * D + d] = (_Float16)(o_acc0[dt][r] * inv_l0[r]);
      Oh[((size_t)(tok0 + 16) * NH + h) * D + d] = (_Float16)(o_acc1[dt][r] * inv_l1[r]);
    }
  }
}

// ---------------------------------------------------------------------------
extern "C" void kernel_launch(void* const* d_in, const int* in_sizes, int n_in,
                              void* d_out, int out_size, void* d_ws, size_t ws_size,
                              hipStream_t stream) {
  const float* hidden    = (const float*)d_in[0];
  const int*   positions = (const int*)d_in[1];
  const float* Wqkv      = (const float*)d_in[2];
  const float* bqkv      = (const float*)d_in[3];
  const float* Wo        = (const float*)d_in[4];
  float* out = (float*)d_out;

  // workspace layout (bytes)
  char* ws = (char*)d_ws;
  _Float16* hs_h  = (_Float16*)(ws);              // 4096x3584 fp16 (later reused as attn out)
  _Float16* Wt    = (_Float16*)(ws + 29360128);   // max 4608x3584 fp16 (Wqkv^T then Wo^T)
  _Float16* qkv_h = (_Float16*)(ws + 62390272);   // 4096x4608 fp16
  _Float16* q_h   = (_Float16*)(ws + 100139008);  // 4096x3584 fp16
  _Float16* k_h   = (_Float16*)(ws + 129499136);  // 4096x512 fp16
  _Float16* vt_h  = (_Float16*)(ws + 133693440);  // 2x4x128x2048 fp16
  // total 137,887,744 bytes

  // 1. hidden fp32 -> fp16
  cast_f32_to_f16<<<14336, 256, 0, stream>>>((const float4*)hidden, (h4*)hs_h, 3670016);
  // 2. Wqkv^T fp16
  transpose_cast<<<dim3(4608 / 32, 3584 / 32), dim3(32, 8), 0, stream>>>(Wqkv, Wt, 3584, 4608);
  // 3. qkv = hidden @ Wqkv + b   (fp16 out) — 128x192 tiles, grid-exact 768
  gemm_wide<<<dim3(24, 32), 256, 0, stream>>>(hs_h, Wt, bqkv, qkv_h, 4096, 4608, 3584);
  // 4a. rope (q,k) — Q pre-scaled; V handled by vtrans
  rope_kernel<<<4096, 256, 0, stream>>>(qkv_h, positions, q_h, k_h);
  // 4b. V transpose (LDS-tiled, coalesced)
  vtrans<<<dim3(64, 16, 2), dim3(32, 8), 0, stream>>>(qkv_h, vt_h);
  // 5. Wo^T fp16 (reuse Wt; stream-ordered after GEMM1)
  transpose_cast<<<dim3(3584 / 32, 3584 / 32), dim3(32, 8), 0, stream>>>(Wo, Wt, 3584, 3584);
  // 6. flash attention -> attn fp16 (into hs_h, dead after GEMM1)
  attn_kernel<<<512, 448, 0, stream>>>(q_h, k_h, vt_h, hs_h);
  // 7. out = attn @ Wo   (fp32 out)
  gemm_kernel<false, false><<<dim3(28, 32), 256, 0, stream>>>(hs_h, Wt, nullptr, out, 4096, 3584, 3584);
}